// Round 10
// baseline (455.251 us; speedup 1.0000x reference)
//
#include <hip/hip_runtime.h>

namespace {

constexpr int Bn = 8192;
constexpr int Tn = 365;
constexpr int Hn = 34;
constexpr int WB = 16;      // batches per wave (= per block; block = 1 wave)
constexpr int KP = 104;     // a_lds row stride in shorts (208 B)
constexpr float L2E = 1.44269504088896340736f;

typedef __attribute__((ext_vector_type(8))) short bf16x8;   // 8 bf16 = 4 VGPR
typedef __attribute__((ext_vector_type(4))) float f32x4;    // 16x16 MFMA acc

__device__ __forceinline__ float fexp2(float v) { return __builtin_amdgcn_exp2f(v); }
__device__ __forceinline__ float frcp(float v)  { return __builtin_amdgcn_rcpf(v); }
__device__ __forceinline__ float sigx(float v)  { return frcp(1.f + fexp2(-L2E * v)); }
__device__ __forceinline__ float tanhx(float v) { return fmaf(-2.f, frcp(1.f + fexp2((2.f * L2E) * v)), 1.f); }

__device__ __forceinline__ unsigned short f2bf(float f) {   // RNE f32->bf16
    union { float f; unsigned u; } v; v.f = f;
    unsigned r = v.u + 0x7fffu + ((v.u >> 16) & 1u);
    return (unsigned short)(r >> 16);
}
__device__ __forceinline__ float bf2f(unsigned short s) {
    union { unsigned u; float f; } v; v.u = ((unsigned)s) << 16; return v.f;
}
// pack h into hi/lo bf16 pair (low short = h_h at even k, high short = h_l)
__device__ __forceinline__ unsigned packh(float h) {
    unsigned short hh = f2bf(h);
    unsigned short hl = f2bf(h - bf2f(hh));
    return (unsigned)hh | ((unsigned)hl << 16);
}

// K-layout (79 used of 96; pads stay zero):
//   k = 2j   : h_h[j] <-> bf16(w_hh[r][j])
//   k = 2j+1 : h_l[j] <-> bf16(w_hh[r][j])
//   k 68-70  : x_h[i] <-> bf16(Wc[r][i])
//   k 71-73  : x_l[i] <-> bf16(Wc[r][i])
//   k 74-76  : x_h[i] <-> bf16(Wc - bf2f(bf16(Wc)))
//   k 77     : 1.0    <-> bias_h
//   k 78     : 1.0    <-> bias_l
// N-packing (D rows): rhat = 4*cell + gate  ->  lane (q=lane>>4) reg r = gate r
// of cell 4*tau+q.  The whole LSTM cell update is lane-local: ZERO barriers.

__global__ __launch_bounds__(64) void lstm_kernel(
    const float* __restrict__ x,      // [B,T,3]
    const float* __restrict__ fc0_w,  // [34,3]
    const float* __restrict__ fc0_b,  // [34]
    const float* __restrict__ w_ih,   // [136,34]
    const float* __restrict__ w_hh,   // [136,34]
    const float* __restrict__ b_ih,   // [136]
    const float* __restrict__ b_hh,   // [136]
    float* __restrict__ out)          // [B,T,34]
{
    __shared__ __align__(16) unsigned short a_lds[2][WB][KP]; // h/x operand, double-buffered

    const int lane = threadIdx.x;   // 0..63 (one wave per block)
    const int b    = lane & 15;     // batch (B-frag col / D col); also A-frag row index
    const int qg   = lane >> 4;     // k-group for operand frags; q for D rows

    // ---- one-time: weight A-fragments Wt[9][3] (row rhat = 16*tau + (lane&15)) ----
    bf16x8 Wt[9][3];
    #pragma unroll
    for (int tau = 0; tau < 9; ++tau) {
        const int rhat = 16 * tau + b;
        const int cell = rhat >> 2, g = rhat & 3;
        const bool valid = (cell < Hn);
        const int r = g * Hn + (valid ? cell : 0);
        float wcv[3] = {0.f, 0.f, 0.f};
        float bia = 0.f;
        if (valid) {
            float ab = 0.f;
            for (int m = 0; m < Hn; ++m) {
                const float wi = w_ih[r * Hn + m];
                wcv[0] += wi * fc0_w[m * 3 + 0];
                wcv[1] += wi * fc0_w[m * 3 + 1];
                wcv[2] += wi * fc0_w[m * 3 + 2];
                ab     += wi * fc0_b[m];
            }
            bia = ab + b_ih[r] + b_hh[r];
        }
        #pragma unroll
        for (int ks = 0; ks < 3; ++ks) {
            bf16x8 f;
            #pragma unroll
            for (int e = 0; e < 8; ++e) {
                const int k = ks * 32 + qg * 8 + e;
                float val = 0.f;
                if (valid) {
                    if (k < 68)       val = w_hh[r * Hn + (k >> 1)];
                    else if (k < 71)  val = wcv[k - 68];
                    else if (k < 74)  val = wcv[k - 71];
                    else if (k < 77)  { const float w = wcv[k - 74]; val = w - bf2f(f2bf(w)); }
                    else if (k == 77) val = bia;                      // bias_h
                    else if (k == 78) val = bia - bf2f(f2bf(bia));    // bias_l
                }
                f[e] = (short)f2bf(val);
            }
            Wt[tau][ks] = f;
        }
    }

    // ---- init LDS (single wave: lgkm fences only, no barrier) ----
    for (int i = lane; i < 2 * WB * KP; i += 64) ((unsigned short*)a_lds)[i] = 0;
    __builtin_amdgcn_sched_barrier(0);
    asm volatile("s_waitcnt lgkmcnt(0)" ::: "memory");
    __builtin_amdgcn_sched_barrier(0);

    if (lane < 32) {   // constant-1.0 slots (bias path), both buffers, never rewritten
        a_lds[lane >> 4][b][77] = (unsigned short)0x3F80;
        a_lds[lane >> 4][b][78] = (unsigned short)0x3F80;
    }
    const int bx = lane / 3, ix = lane - 3 * (lane / 3);   // x staging (lane<48)
    const float* xw = x + ((long long)blockIdx.x * WB) * (Tn * 3);
    if (lane < 48) {
        const float xr = xw[bx * (Tn * 3) + ix];
        const unsigned short xh = f2bf(xr);
        a_lds[0][bx][68 + ix] = xh;
        a_lds[0][bx][71 + ix] = f2bf(xr - bf2f(xh));
        a_lds[0][bx][74 + ix] = xh;
    }

    float* pout = out + ((long long)blockIdx.x * WB + b) * ((long long)Tn * Hn) + qg;
    float cst[9] = {0.f, 0.f, 0.f, 0.f, 0.f, 0.f, 0.f, 0.f, 0.f};

    for (int t = 0; t < Tn; ++t) {
        const int cur = t & 1, nxt = cur ^ 1;

        // intra-wave fence: prior packh/x writes -> this step's reads (rule #18)
        __builtin_amdgcn_sched_barrier(0);
        asm volatile("s_waitcnt lgkmcnt(0)" ::: "memory");
        __builtin_amdgcn_sched_barrier(0);

        // B-fragments (h/x data): col = b, k-chunk ks at shorts ks*32 + qg*8
        bf16x8 av[3];
        #pragma unroll
        for (int ks = 0; ks < 3; ++ks)
            av[ks] = *(const bf16x8*)(&a_lds[cur][b][ks * 32 + qg * 8]);

        // prefetch next step's x
        float xr = 0.f;
        if (lane < 48 && t + 1 < Tn)
            xr = xw[bx * (Tn * 3) + (t + 1) * 3 + ix];

        // 9 tiles: D = W*h; lane (q,b) regs = gates i,f,g,o of cell 4*tau+q, batch b
        #pragma unroll
        for (int tau = 0; tau < 9; ++tau) {
            f32x4 acc = {0.f, 0.f, 0.f, 0.f};
            #pragma unroll
            for (int ks = 0; ks < 3; ++ks)
                acc = __builtin_amdgcn_mfma_f32_16x16x32_bf16(Wt[tau][ks], av[ks], acc, 0, 0, 0);
            const float gi = sigx(acc[0]);
            const float gf = sigx(acc[1]);
            const float gg = tanhx(acc[2]);
            const float go = sigx(acc[3]);
            cst[tau] = gf * cst[tau] + gi * gg;
            const float h = go * tanhx(cst[tau]);
            if (tau < 8 || qg < 2) {   // tile 8: only cells 32,33 exist
                ((unsigned*)&a_lds[nxt][b][0])[4 * tau + qg] = packh(h);
                pout[(long long)t * Hn + 4 * tau] = h;
            }
        }

        // stage x(t+1) into next buffer
        if (lane < 48) {
            const unsigned short xh = f2bf(xr);
            a_lds[nxt][bx][68 + ix] = xh;
            a_lds[nxt][bx][71 + ix] = f2bf(xr - bf2f(xh));
            a_lds[nxt][bx][74 + ix] = xh;
        }
    }
}

} // namespace

extern "C" void kernel_launch(void* const* d_in, const int* in_sizes, int n_in,
                              void* d_out, int out_size, void* d_ws, size_t ws_size,
                              hipStream_t stream) {
    const float* x     = (const float*)d_in[0];
    const float* fc0_w = (const float*)d_in[1];
    const float* fc0_b = (const float*)d_in[2];
    const float* w_ih  = (const float*)d_in[3];
    const float* w_hh  = (const float*)d_in[4];
    const float* b_ih  = (const float*)d_in[5];
    const float* b_hh  = (const float*)d_in[6];
    float* out = (float*)d_out;

    lstm_kernel<<<Bn / WB, 64, 0, stream>>>(x, fc0_w, fc0_b, w_ih, w_hh, b_ih, b_hh, out);
}